// Round 1
// baseline (16255.527 us; speedup 1.0000x reference)
//
#include <hip/hip_runtime.h>
#include <math.h>

constexpr int N_TOK = 8192;
constexpr int DIM   = 1024;
constexpr float SCALE = 0.03125f; // 1/sqrt(1024)

// ---------------- Projection GEMM: C[M,N] = A[M,K] @ B[K,N] ----------------
// M=8192, N=K=1024. Classic 128x128x8 tile, 8x8 microtile, 256 threads.
__global__ __launch_bounds__(256, 2) void sgemm_proj(const float* __restrict__ A,
                                                     const float* __restrict__ B,
                                                     float* __restrict__ C) {
  constexpr int Nn = DIM, Kk = DIM;
  constexpr int BMt = 128, BNt = 128, BKt = 8, TMt = 8, TNt = 8;
  __shared__ float As[BKt][BMt];
  __shared__ float Bs[BKt][BNt];
  const int tid = threadIdx.x;
  const int bx = blockIdx.x, by = blockIdx.y;
  const int tx = tid & 15, ty = tid >> 4;
  float acc[TMt][TNt] = {};
  const float* Ab = A + (size_t)by * BMt * Kk;
  const float* Bb = B + (size_t)bx * BNt;
  const int arow = tid >> 1, acol = (tid & 1) * 4;
  const int brow = tid >> 5, bcol = (tid & 31) * 4;
  for (int k0 = 0; k0 < Kk; k0 += BKt) {
    float4 a4 = *(const float4*)(Ab + (size_t)arow * Kk + k0 + acol);
    As[acol + 0][arow] = a4.x;
    As[acol + 1][arow] = a4.y;
    As[acol + 2][arow] = a4.z;
    As[acol + 3][arow] = a4.w;
    *(float4*)&Bs[brow][bcol] = *(const float4*)(Bb + (size_t)(k0 + brow) * Nn + bcol);
    __syncthreads();
#pragma unroll
    for (int kk = 0; kk < BKt; ++kk) {
      float ra[TMt], rb[TNt];
      *(float4*)&ra[0] = *(float4*)&As[kk][ty * TMt];
      *(float4*)&ra[4] = *(float4*)&As[kk][ty * TMt + 4];
      *(float4*)&rb[0] = *(float4*)&Bs[kk][tx * TNt];
      *(float4*)&rb[4] = *(float4*)&Bs[kk][tx * TNt + 4];
#pragma unroll
      for (int i = 0; i < TMt; ++i)
#pragma unroll
        for (int j = 0; j < TNt; ++j) acc[i][j] = fmaf(ra[i], rb[j], acc[i][j]);
    }
    __syncthreads();
  }
  float* Cb = C + (size_t)(by * BMt + ty * TMt) * Nn + (size_t)bx * BNt + tx * TNt;
#pragma unroll
  for (int i = 0; i < TMt; ++i)
#pragma unroll
    for (int j = 0; j < TNt; j += 4) {
      float4 v = make_float4(acc[i][j], acc[i][j + 1], acc[i][j + 2], acc[i][j + 3]);
      *(float4*)(Cb + (size_t)i * Nn + j) = v;
    }
}

// ---------------- Flash attention (fp32, V = X) ----------------
// Grid: 512 blocks (16 q-rows each), 256 threads (4 waves).
// Wave w owns q-rows w*4..w*4+3 completely: S rows, softmax state, O rows.
__global__ __launch_bounds__(256, 2) void flash_attn(const float* __restrict__ Q,
                                                     const float* __restrict__ K,
                                                     const float* __restrict__ X,
                                                     float* __restrict__ Out) {
  constexpr int BM = 16, BN = 64, DK = 64, CC = 256;
  __shared__ union {
    struct {
      float Qc[BM][DK];      // 4 KB
      float Kc[BN][DK + 4];  // 17.4 KB (pad: row stride 272B = odd # of 16B superbanks)
    } a;
    float Xs[BN][CC];        // 64 KB
  } U;
  __shared__ float Pt[BN][BM + 4];  // 5 KB, padded (row stride 80B) for conflict-free b128

  const int t = threadIdx.x;
  const int qb = blockIdx.x;
  const int w = t >> 6;    // wave id 0..3 -> q-rows w*4 .. w*4+3
  const int lane = t & 63; // k-col within tile / O-col group
  const int qrow0 = qb * BM;

  float m_i[4], l_i[4];
  float acc[4][4][4];  // [col-chunk][row][col]
#pragma unroll
  for (int i = 0; i < 4; ++i) { m_i[i] = -INFINITY; l_i[i] = 0.f; }
#pragma unroll
  for (int cc = 0; cc < 4; ++cc)
#pragma unroll
    for (int i = 0; i < 4; ++i)
#pragma unroll
      for (int c = 0; c < 4; ++c) acc[cc][i][c] = 0.f;

  for (int kt = 0; kt < N_TOK / BN; ++kt) {
    // ---- Phase A: S[16][64] = Q_blk @ K_tile^T ----
    float s[4] = {0.f, 0.f, 0.f, 0.f};
    for (int d0 = 0; d0 < DIM; d0 += DK) {
      __syncthreads();  // also guards Xs -> Qc/Kc reuse from previous tile
      {
        int r = t >> 4, c = (t & 15) * 4;
        *(float4*)&U.a.Qc[r][c] = *(const float4*)&Q[(size_t)(qrow0 + r) * DIM + d0 + c];
      }
#pragma unroll
      for (int rep = 0; rep < 4; ++rep) {
        int r = (t >> 4) + rep * 16, c = (t & 15) * 4;
        *(float4*)&U.a.Kc[r][c] = *(const float4*)&K[(size_t)(kt * BN + r) * DIM + d0 + c];
      }
      __syncthreads();
#pragma unroll
      for (int d = 0; d < DK; d += 4) {
        float4 kv = *(float4*)&U.a.Kc[lane][d];
#pragma unroll
        for (int i = 0; i < 4; ++i) {
          float4 qv = *(float4*)&U.a.Qc[w * 4 + i][d];
          s[i] = fmaf(qv.x, kv.x, s[i]);
          s[i] = fmaf(qv.y, kv.y, s[i]);
          s[i] = fmaf(qv.z, kv.z, s[i]);
          s[i] = fmaf(qv.w, kv.w, s[i]);
        }
      }
    }

    // ---- Phase B: online softmax, fully wave-local ----
    float alpha[4];
    float p4[4];
#pragma unroll
    for (int i = 0; i < 4; ++i) {
      float sc = s[i] * SCALE;
      float mt = sc;
#pragma unroll
      for (int off = 32; off >= 1; off >>= 1) mt = fmaxf(mt, __shfl_xor(mt, off, 64));
      float m_new = fmaxf(m_i[i], mt);
      alpha[i] = expf(m_i[i] - m_new);  // exp(-inf - finite) = 0 on first tile
      float p = expf(sc - m_new);
      float ls = p;
#pragma unroll
      for (int off = 32; off >= 1; off >>= 1) ls += __shfl_xor(ls, off, 64);
      l_i[i] = l_i[i] * alpha[i] + ls;
      m_i[i] = m_new;
      p4[i] = p;
    }
    *(float4*)&Pt[lane][w * 4] = make_float4(p4[0], p4[1], p4[2], p4[3]);

    // ---- Phase C: O[16][1024] = alpha*O + P @ X_tile ----
#pragma unroll
    for (int cc = 0; cc < 4; ++cc)
#pragma unroll
      for (int i = 0; i < 4; ++i)
#pragma unroll
        for (int c = 0; c < 4; ++c) acc[cc][i][c] *= alpha[i];

    for (int cc = 0; cc < 4; ++cc) {
      __syncthreads();  // all waves done with Kc/Qc (or previous Xs)
#pragma unroll
      for (int rep = 0; rep < 16; ++rep) {
        int idx = rep * 256 + t;
        int r = idx >> 6;
        int c = (idx & 63) * 4;
        *(float4*)&U.Xs[r][c] =
            *(const float4*)&X[(size_t)(kt * BN + r) * DIM + cc * CC + c];
      }
      __syncthreads();
#pragma unroll 8
      for (int j = 0; j < BN; ++j) {
        float4 pv = *(float4*)&Pt[j][w * 4];   // broadcast within wave
        float4 xv = *(float4*)&U.Xs[j][lane * 4];
        float pr[4] = {pv.x, pv.y, pv.z, pv.w};
        float xr[4] = {xv.x, xv.y, xv.z, xv.w};
#pragma unroll
        for (int i = 0; i < 4; ++i)
#pragma unroll
          for (int c = 0; c < 4; ++c) acc[cc][i][c] = fmaf(pr[i], xr[c], acc[cc][i][c]);
      }
    }
  }

  // ---- Epilogue: normalize and store ----
#pragma unroll
  for (int i = 0; i < 4; ++i) {
    float inv = 1.f / l_i[i];
    float* orow = Out + (size_t)(qrow0 + w * 4 + i) * DIM;
#pragma unroll
    for (int cc = 0; cc < 4; ++cc) {
      float4 v = make_float4(acc[cc][i][0] * inv, acc[cc][i][1] * inv,
                             acc[cc][i][2] * inv, acc[cc][i][3] * inv);
      *(float4*)&orow[cc * CC + lane * 4] = v;
    }
  }
}

extern "C" void kernel_launch(void* const* d_in, const int* in_sizes, int n_in,
                              void* d_out, int out_size, void* d_ws, size_t ws_size,
                              hipStream_t stream) {
  const float* Wq = (const float*)d_in[0];  // rotation_params [1024,1024]
  const float* Wk = (const float*)d_in[1];  // entangle_params [1024,1024]
  const float* X  = (const float*)d_in[2];  // inputs [8192,1024]
  float* Out = (float*)d_out;               // [8192,1024] fp32

  float* Q  = (float*)d_ws;                 // 32 MB
  float* Kp = Q + (size_t)N_TOK * DIM;      // 32 MB

  dim3 gproj(DIM / 128, N_TOK / 128);
  sgemm_proj<<<gproj, 256, 0, stream>>>(X, Wq, Q);
  sgemm_proj<<<gproj, 256, 0, stream>>>(X, Wk, Kp);
  flash_attn<<<dim3(N_TOK / 16), 256, 0, stream>>>(Q, Kp, X, Out);
}

// Round 2
// 3243.493 us; speedup vs baseline: 5.0117x; 5.0117x over previous
//
#include <hip/hip_runtime.h>
#include <math.h>

typedef unsigned short u16;
typedef __bf16 bf16x8 __attribute__((ext_vector_type(8)));
typedef float floatx16 __attribute__((ext_vector_type(16)));

constexpr int N_TOK = 8192;
constexpr int DIM   = 1024;
// softmax computed in exp2 domain: s2 = dot * (1/sqrt(1024)) * log2(e)
constexpr float SC2 = 0.03125f * 1.4426950408889634f;

__device__ __forceinline__ u16 f2bf(float f) {
  unsigned u = __builtin_bit_cast(unsigned, f);
  unsigned r = u + 0x7fffu + ((u >> 16) & 1u);  // round-to-nearest-even
  return (u16)(r >> 16);
}
__device__ __forceinline__ float bf2f(u16 h) {
  unsigned u = ((unsigned)h) << 16;
  return __builtin_bit_cast(float, u);
}
__device__ __forceinline__ bf16x8 ld16g(const u16* p) {
  return *reinterpret_cast<const bf16x8*>(p);
}

// ---------------- Projection GEMM with hi/lo bf16 split epilogue ----------
// C = A[8192,1024] @ B[1024,1024]; writes Chi/Clo bf16 (C = Chi + Clo, ~2^-17 rel).
__global__ __launch_bounds__(256, 2) void sgemm_split(const float* __restrict__ A,
                                                      const float* __restrict__ B,
                                                      u16* __restrict__ Chi,
                                                      u16* __restrict__ Clo) {
  constexpr int Nn = DIM, Kk = DIM;
  constexpr int BMt = 128, BNt = 128, BKt = 8, TMt = 8, TNt = 8;
  __shared__ float As[BKt][BMt];
  __shared__ float Bs[BKt][BNt];
  const int tid = threadIdx.x;
  const int bx = blockIdx.x, by = blockIdx.y;
  const int tx = tid & 15, ty = tid >> 4;
  float acc[TMt][TNt] = {};
  const float* Ab = A + (size_t)by * BMt * Kk;
  const float* Bb = B + (size_t)bx * BNt;
  const int arow = tid >> 1, acol = (tid & 1) * 4;
  const int brow = tid >> 5, bcol = (tid & 31) * 4;
  for (int k0 = 0; k0 < Kk; k0 += BKt) {
    float4 a4 = *(const float4*)(Ab + (size_t)arow * Kk + k0 + acol);
    As[acol + 0][arow] = a4.x;
    As[acol + 1][arow] = a4.y;
    As[acol + 2][arow] = a4.z;
    As[acol + 3][arow] = a4.w;
    *(float4*)&Bs[brow][bcol] = *(const float4*)(Bb + (size_t)(k0 + brow) * Nn + bcol);
    __syncthreads();
#pragma unroll
    for (int kk = 0; kk < BKt; ++kk) {
      float ra[TMt], rb[TNt];
      *(float4*)&ra[0] = *(float4*)&As[kk][ty * TMt];
      *(float4*)&ra[4] = *(float4*)&As[kk][ty * TMt + 4];
      *(float4*)&rb[0] = *(float4*)&Bs[kk][tx * TNt];
      *(float4*)&rb[4] = *(float4*)&Bs[kk][tx * TNt + 4];
#pragma unroll
      for (int i = 0; i < TMt; ++i)
#pragma unroll
        for (int j = 0; j < TNt; ++j) acc[i][j] = fmaf(ra[i], rb[j], acc[i][j]);
    }
    __syncthreads();
  }
  const int colbase = bx * BNt + tx * TNt;
#pragma unroll
  for (int i = 0; i < TMt; ++i) {
    u16 h[8], l[8];
#pragma unroll
    for (int j = 0; j < TNt; ++j) {
      float v = acc[i][j];
      h[j] = f2bf(v);
      l[j] = f2bf(v - bf2f(h[j]));
    }
    size_t off = (size_t)(by * BMt + ty * TMt + i) * Nn + colbase;
    uint4 hv, lv;
    hv.x = (unsigned)h[0] | ((unsigned)h[1] << 16);
    hv.y = (unsigned)h[2] | ((unsigned)h[3] << 16);
    hv.z = (unsigned)h[4] | ((unsigned)h[5] << 16);
    hv.w = (unsigned)h[6] | ((unsigned)h[7] << 16);
    lv.x = (unsigned)l[0] | ((unsigned)l[1] << 16);
    lv.y = (unsigned)l[2] | ((unsigned)l[3] << 16);
    lv.z = (unsigned)l[4] | ((unsigned)l[5] << 16);
    lv.w = (unsigned)l[6] | ((unsigned)l[7] << 16);
    *(uint4*)(Chi + off) = hv;
    *(uint4*)(Clo + off) = lv;
  }
}

// ---------------- X -> Xt (bf16, transposed [DIM][N_TOK]) ----------------
__global__ __launch_bounds__(256, 4) void transpose_bf16(const float* __restrict__ X,
                                                         u16* __restrict__ Xt) {
  __shared__ u16 T[64][72];  // row stride 144B = 9 x 16B -> conflict-light
  const int tok0 = blockIdx.x * 64, d0 = blockIdx.y * 64;
  const int t = threadIdx.x;
  {
    const int tok = t >> 2, dc = (t & 3) * 16;
    const float* src = X + (size_t)(tok0 + tok) * DIM + d0 + dc;
    float4 v0 = *(const float4*)(src + 0);
    float4 v1 = *(const float4*)(src + 4);
    float4 v2 = *(const float4*)(src + 8);
    float4 v3 = *(const float4*)(src + 12);
    float vv[16] = {v0.x, v0.y, v0.z, v0.w, v1.x, v1.y, v1.z, v1.w,
                    v2.x, v2.y, v2.z, v2.w, v3.x, v3.y, v3.z, v3.w};
#pragma unroll
    for (int c = 0; c < 16; ++c) T[dc + c][tok] = f2bf(vv[c]);
  }
  __syncthreads();
  {
    const int d = t >> 3, tk = (t & 7) * 8;
#pragma unroll
    for (int rep = 0; rep < 2; ++rep) {
      int dd = d + rep * 32;
      *(uint4*)(Xt + (size_t)(d0 + dd) * N_TOK + tok0 + tk) = *(uint4*)&T[dd][tk];
    }
  }
}

// ---------------- MFMA flash attention ----------------
// 256 blocks x 256 threads. Block owns 32 q-rows. Per kt iteration the 4 waves
// cover 128 k-tokens (one 32x32 S tile each, split-bf16 QK^T = 3 MFMAs/kstep).
// Each wave owns a 256-wide d-slice of O (8 C-tiles, 128 acc regs).
__global__ __launch_bounds__(256, 1) void flash_mfma(const u16* __restrict__ Qhi,
                                                     const u16* __restrict__ Qlo,
                                                     const u16* __restrict__ Khi,
                                                     const u16* __restrict__ Klo,
                                                     const u16* __restrict__ Xt,
                                                     float* __restrict__ Out) {
  __shared__ u16 Pb[32][264];  // P in [q-row][token] bf16; stride 528B = 33x16B
  __shared__ float red_max[4][32], red_sum[4][32];
  __shared__ float m2_run[32], l_run[32], alpha_s[32], m2new_s[32];

  const int t = threadIdx.x;
  const int w = t >> 6, lane = t & 63;
  const int half = lane >> 5, l31 = lane & 31;
  const int qrow0 = blockIdx.x * 32;

  floatx16 O[8] = {};
  if (t < 32) { m2_run[t] = -INFINITY; l_run[t] = 0.f; }
  __syncthreads();

  const u16* qh = Qhi + (size_t)(qrow0 + l31) * DIM + half * 8;
  const u16* ql = Qlo + (size_t)(qrow0 + l31) * DIM + half * 8;

  for (int kt = 0; kt < N_TOK / 128; ++kt) {
    // ---- Phase A: S[32][32] per wave, K-dim = full 1024 ----
    floatx16 S = {};
    const int tok0 = kt * 128 + w * 32;
    const u16* kh = Khi + (size_t)(tok0 + l31) * DIM + half * 8;
    const u16* kl = Klo + (size_t)(tok0 + l31) * DIM + half * 8;
#pragma unroll 4
    for (int ks = 0; ks < DIM / 16; ++ks) {
      bf16x8 aH = ld16g(qh + ks * 16);
      bf16x8 aL = ld16g(ql + ks * 16);
      bf16x8 bH = ld16g(kh + ks * 16);
      bf16x8 bL = ld16g(kl + ks * 16);
      S = __builtin_amdgcn_mfma_f32_32x32x16_bf16(aH, bH, S, 0, 0, 0);
      S = __builtin_amdgcn_mfma_f32_32x32x16_bf16(aH, bL, S, 0, 0, 0);
      S = __builtin_amdgcn_mfma_f32_32x32x16_bf16(aL, bH, S, 0, 0, 0);
    }

    // ---- Phase B: block online softmax (exp2 domain) ----
    float s2[16];
#pragma unroll
    for (int r = 0; r < 16; ++r) {
      s2[r] = S[r] * SC2;
      float m = s2[r];
#pragma unroll
      for (int off = 16; off >= 1; off >>= 1) m = fmaxf(m, __shfl_xor(m, off, 32));
      if (l31 == 0) red_max[w][(r & 3) + 8 * (r >> 2) + 4 * half] = m;
    }
    __syncthreads();  // b1
    if (t < 32) {
      float tm = fmaxf(fmaxf(red_max[0][t], red_max[1][t]),
                       fmaxf(red_max[2][t], red_max[3][t]));
      float mo = m2_run[t];
      float mn = fmaxf(mo, tm);
      m2new_s[t] = mn;
      alpha_s[t] = __builtin_amdgcn_exp2f(mo - mn);
      m2_run[t] = mn;
    }
    __syncthreads();  // b2
    float p[16];
#pragma unroll
    for (int r = 0; r < 16; ++r) {
      int row = (r & 3) + 8 * (r >> 2) + 4 * half;
      float pv = __builtin_amdgcn_exp2f(s2[r] - m2new_s[row]);
      u16 h = f2bf(pv);
      p[r] = bf2f(h);  // keep l consistent with what P@X actually uses
      Pb[row][w * 32 + l31] = h;
    }
#pragma unroll
    for (int r = 0; r < 16; ++r) {
      float sm = p[r];
#pragma unroll
      for (int off = 16; off >= 1; off >>= 1) sm += __shfl_xor(sm, off, 32);
      if (l31 == 0) red_sum[w][(r & 3) + 8 * (r >> 2) + 4 * half] = sm;
    }
    // rescale O by alpha (row-mapped identically to C layout)
#pragma unroll
    for (int r = 0; r < 16; ++r) {
      float a = alpha_s[(r & 3) + 8 * (r >> 2) + 4 * half];
#pragma unroll
      for (int nt = 0; nt < 8; ++nt) O[nt][r] *= a;
    }
    __syncthreads();  // b3: Pb + red_sum visible
    if (t < 32)
      l_run[t] = l_run[t] * alpha_s[t] +
                 (red_sum[0][t] + red_sum[1][t]) + (red_sum[2][t] + red_sum[3][t]);

    // ---- Phase C: O[32][w's 256 cols] += P[32][128] @ X[128 tok][cols] ----
    const u16* xb = Xt + (size_t)(w * 256 + l31) * N_TOK + kt * 128 + half * 8;
    for (int ks = 0; ks < 8; ++ks) {
      bf16x8 aP = *reinterpret_cast<const bf16x8*>(&Pb[l31][ks * 16 + half * 8]);
#pragma unroll
      for (int nt = 0; nt < 8; ++nt) {
        bf16x8 bX = ld16g(xb + (size_t)nt * 32 * N_TOK + ks * 16);
        O[nt] = __builtin_amdgcn_mfma_f32_32x32x16_bf16(aP, bX, O[nt], 0, 0, 0);
      }
    }
  }

  __syncthreads();  // final l_run visible
#pragma unroll
  for (int r = 0; r < 16; ++r) {
    int row = (r & 3) + 8 * (r >> 2) + 4 * half;
    float inv = 1.0f / l_run[row];
    float* orow = Out + (size_t)(qrow0 + row) * DIM + w * 256 + l31;
#pragma unroll
    for (int nt = 0; nt < 8; ++nt) orow[nt * 32] = O[nt][r] * inv;
  }
}

extern "C" void kernel_launch(void* const* d_in, const int* in_sizes, int n_in,
                              void* d_out, int out_size, void* d_ws, size_t ws_size,
                              hipStream_t stream) {
  const float* Wq = (const float*)d_in[0];
  const float* Wk = (const float*)d_in[1];
  const float* X  = (const float*)d_in[2];
  float* Out = (float*)d_out;

  constexpr size_t MAT = (size_t)N_TOK * DIM;  // 8M elements
  u16* Qhi = (u16*)d_ws;
  u16* Qlo = Qhi + MAT;
  u16* Khi = Qlo + MAT;
  u16* Klo = Khi + MAT;
  u16* Xt  = Klo + MAT;  // [DIM][N_TOK]; total ws use = 80 MB

  dim3 gproj(DIM / 128, N_TOK / 128);
  sgemm_split<<<gproj, 256, 0, stream>>>(X, Wq, Qhi, Qlo);
  sgemm_split<<<gproj, 256, 0, stream>>>(X, Wk, Khi, Klo);
  transpose_bf16<<<dim3(N_TOK / 64, DIM / 64), 256, 0, stream>>>(X, Xt);
  flash_mfma<<<dim3(N_TOK / 32), 256, 0, stream>>>(Qhi, Qlo, Khi, Klo, Xt, Out);
}

// Round 3
// 1185.582 us; speedup vs baseline: 13.7110x; 2.7358x over previous
//
#include <hip/hip_runtime.h>
#include <math.h>

typedef unsigned short u16;
typedef __bf16 bf16x8 __attribute__((ext_vector_type(8)));
typedef float floatx4 __attribute__((ext_vector_type(4)));

constexpr int N_TOK = 8192;
constexpr int DIM   = 1024;
// softmax in exp2 domain: s2 = dot * (1/sqrt(1024)) * log2(e)
constexpr float SC2 = 0.03125f * 1.4426950408889634f;

__device__ __forceinline__ u16 f2bf(float f) {
  unsigned u = __builtin_bit_cast(unsigned, f);
  unsigned r = u + 0x7fffu + ((u >> 16) & 1u);  // round-to-nearest-even
  return (u16)(r >> 16);
}
__device__ __forceinline__ float bf2f(u16 h) {
  unsigned u = ((unsigned)h) << 16;
  return __builtin_bit_cast(float, u);
}
__device__ __forceinline__ floatx4 mfma16(bf16x8 a, bf16x8 b, floatx4 c) {
  return __builtin_amdgcn_mfma_f32_16x16x32_bf16(a, b, c, 0, 0, 0);
}
// async global->LDS, 16B per lane. Global side: per-lane address; LDS side:
// wave-uniform base + lane*16 (m104 semantics).
__device__ __forceinline__ void gload_lds16(const void* g, void* l) {
  using GP = const unsigned __attribute__((address_space(1)))*;
  using LP = unsigned __attribute__((address_space(3)))*;
  __builtin_amdgcn_global_load_lds((GP)(uintptr_t)g, (LP)(uintptr_t)l, 16, 0, 0);
}

// ---------------- Projection GEMM with hi/lo bf16 split epilogue ----------
__global__ __launch_bounds__(256, 2) void sgemm_split(const float* __restrict__ A,
                                                      const float* __restrict__ B,
                                                      u16* __restrict__ Chi,
                                                      u16* __restrict__ Clo) {
  constexpr int Nn = DIM, Kk = DIM;
  constexpr int BMt = 128, BNt = 128, BKt = 8, TMt = 8, TNt = 8;
  __shared__ float As[BKt][BMt];
  __shared__ float Bs[BKt][BNt];
  const int tid = threadIdx.x;
  const int bx = blockIdx.x, by = blockIdx.y;
  const int tx = tid & 15, ty = tid >> 4;
  float acc[TMt][TNt] = {};
  const float* Ab = A + (size_t)by * BMt * Kk;
  const float* Bb = B + (size_t)bx * BNt;
  const int arow = tid >> 1, acol = (tid & 1) * 4;
  const int brow = tid >> 5, bcol = (tid & 31) * 4;
  for (int k0 = 0; k0 < Kk; k0 += BKt) {
    float4 a4 = *(const float4*)(Ab + (size_t)arow * Kk + k0 + acol);
    As[acol + 0][arow] = a4.x;
    As[acol + 1][arow] = a4.y;
    As[acol + 2][arow] = a4.z;
    As[acol + 3][arow] = a4.w;
    *(float4*)&Bs[brow][bcol] = *(const float4*)(Bb + (size_t)(k0 + brow) * Nn + bcol);
    __syncthreads();
#pragma unroll
    for (int kk = 0; kk < BKt; ++kk) {
      float ra[TMt], rb[TNt];
      *(float4*)&ra[0] = *(float4*)&As[kk][ty * TMt];
      *(float4*)&ra[4] = *(float4*)&As[kk][ty * TMt + 4];
      *(float4*)&rb[0] = *(float4*)&Bs[kk][tx * TNt];
      *(float4*)&rb[4] = *(float4*)&Bs[kk][tx * TNt + 4];
#pragma unroll
      for (int i = 0; i < TMt; ++i)
#pragma unroll
        for (int j = 0; j < TNt; ++j) acc[i][j] = fmaf(ra[i], rb[j], acc[i][j]);
    }
    __syncthreads();
  }
  const int colbase = bx * BNt + tx * TNt;
#pragma unroll
  for (int i = 0; i < TMt; ++i) {
    u16 h[8], l[8];
#pragma unroll
    for (int j = 0; j < TNt; ++j) {
      float v = acc[i][j];
      h[j] = f2bf(v);
      l[j] = f2bf(v - bf2f(h[j]));
    }
    size_t off = (size_t)(by * BMt + ty * TMt + i) * Nn + colbase;
    uint4 hv, lv;
    hv.x = (unsigned)h[0] | ((unsigned)h[1] << 16);
    hv.y = (unsigned)h[2] | ((unsigned)h[3] << 16);
    hv.z = (unsigned)h[4] | ((unsigned)h[5] << 16);
    hv.w = (unsigned)h[6] | ((unsigned)h[7] << 16);
    lv.x = (unsigned)l[0] | ((unsigned)l[1] << 16);
    lv.y = (unsigned)l[2] | ((unsigned)l[3] << 16);
    lv.z = (unsigned)l[4] | ((unsigned)l[5] << 16);
    lv.w = (unsigned)l[6] | ((unsigned)l[7] << 16);
    *(uint4*)(Chi + off) = hv;
    *(uint4*)(Clo + off) = lv;
  }
}

// ---------------- X -> Xt (bf16, transposed [DIM][N_TOK]) ----------------
__global__ __launch_bounds__(256, 4) void transpose_bf16(const float* __restrict__ X,
                                                         u16* __restrict__ Xt) {
  __shared__ u16 T[64][72];
  const int tok0 = blockIdx.x * 64, d0 = blockIdx.y * 64;
  const int t = threadIdx.x;
  {
    const int tok = t >> 2, dc = (t & 3) * 16;
    const float* src = X + (size_t)(tok0 + tok) * DIM + d0 + dc;
    float4 v0 = *(const float4*)(src + 0);
    float4 v1 = *(const float4*)(src + 4);
    float4 v2 = *(const float4*)(src + 8);
    float4 v3 = *(const float4*)(src + 12);
    float vv[16] = {v0.x, v0.y, v0.z, v0.w, v1.x, v1.y, v1.z, v1.w,
                    v2.x, v2.y, v2.z, v2.w, v3.x, v3.y, v3.z, v3.w};
#pragma unroll
    for (int c = 0; c < 16; ++c) T[dc + c][tok] = f2bf(vv[c]);
  }
  __syncthreads();
  {
    const int d = t >> 3, tk = (t & 7) * 8;
#pragma unroll
    for (int rep = 0; rep < 2; ++rep) {
      int dd = d + rep * 32;
      *(uint4*)(Xt + (size_t)(d0 + dd) * N_TOK + tok0 + tk) = *(uint4*)&T[dd][tk];
    }
  }
}

// ---------------- Pass S: P' = exp2(QK^T*SC2 - mb), Mpart, Lpart ---------
// m97-shape: 128x128 tile, BK=32, 16x16x32 mfma, split-3 bf16.
__global__ __launch_bounds__(256, 2) void gemm_s(const u16* __restrict__ Qhi,
                                                 const u16* __restrict__ Qlo,
                                                 const u16* __restrict__ Khi,
                                                 const u16* __restrict__ Klo,
                                                 u16* __restrict__ P,
                                                 float* __restrict__ Mpart,
                                                 float* __restrict__ Lpart) {
  __shared__ u16 T[4][128 * 32];  // Ahi, Alo, Bhi, Blo
  __shared__ float Mw[2][128], Lw[2][128];
  const int t = threadIdx.x, w = t >> 6, l = t & 63;
  const int l15 = l & 15, l4 = l >> 4;
  const int cb = blockIdx.x, rb = blockIdx.y;  // col-block (k tokens), row-block (q)
  const int wm = w & 1, wn = w >> 1;

  const u16* sbase;
  if (w == 0)      sbase = Qhi + (size_t)rb * 128 * DIM;
  else if (w == 1) sbase = Qlo + (size_t)rb * 128 * DIM;
  else if (w == 2) sbase = Khi + (size_t)cb * 128 * DIM;
  else             sbase = Klo + (size_t)cb * 128 * DIM;
  const u16* mysrc = sbase + (size_t)(l >> 2) * DIM + (l & 3) * 8;

  floatx4 acc[4][4] = {};

  for (int k0 = 0; k0 < DIM; k0 += 32) {
    __syncthreads();
#pragma unroll
    for (int n = 0; n < 8; ++n)
      gload_lds16(mysrc + (size_t)n * 16 * DIM + k0, &T[w][n * 512]);
    __syncthreads();
    bf16x8 aH[4], aL[4], bH[4], bL[4];
#pragma unroll
    for (int i = 0; i < 4; ++i) {
      int ar = wm * 64 + i * 16 + l15;
      aH[i] = *(const bf16x8*)&T[0][ar * 32 + l4 * 8];
      aL[i] = *(const bf16x8*)&T[1][ar * 32 + l4 * 8];
      int br = wn * 64 + i * 16 + l15;
      bH[i] = *(const bf16x8*)&T[2][br * 32 + l4 * 8];
      bL[i] = *(const bf16x8*)&T[3][br * 32 + l4 * 8];
    }
#pragma unroll
    for (int i = 0; i < 4; ++i)
#pragma unroll
      for (int j = 0; j < 4; ++j) {
        acc[i][j] = mfma16(aL[i], bH[j], acc[i][j]);
        acc[i][j] = mfma16(aH[i], bL[j], acc[i][j]);
        acc[i][j] = mfma16(aH[i], bH[j], acc[i][j]);
      }
  }

  // ---- epilogue ----
  // scale into exp2 domain
#pragma unroll
  for (int i = 0; i < 4; ++i)
#pragma unroll
    for (int j = 0; j < 4; ++j)
#pragma unroll
      for (int r = 0; r < 4; ++r) acc[i][j][r] *= SC2;

  // per-row max over this block's 128 cols
  float mrow[4][4];
#pragma unroll
  for (int i = 0; i < 4; ++i)
#pragma unroll
    for (int r = 0; r < 4; ++r) {
      float m = fmaxf(fmaxf(acc[i][0][r], acc[i][1][r]),
                      fmaxf(acc[i][2][r], acc[i][3][r]));
#pragma unroll
      for (int off = 1; off <= 8; off <<= 1) m = fmaxf(m, __shfl_xor(m, off, 64));
      mrow[i][r] = m;
      if (l15 == 0) Mw[wn][wm * 64 + i * 16 + l4 * 4 + r] = m;
    }
  __syncthreads();
  // combine the two wn waves' maxes, write P' and row-sums
  float lsum[4][4];
#pragma unroll
  for (int i = 0; i < 4; ++i)
#pragma unroll
    for (int r = 0; r < 4; ++r) {
      int lr = wm * 64 + i * 16 + l4 * 4 + r;
      float mb = fmaxf(Mw[0][lr], Mw[1][lr]);
      mrow[i][r] = mb;
      float ls = 0.f;
      size_t R = (size_t)(rb * 128 + lr);
#pragma unroll
      for (int j = 0; j < 4; ++j) {
        float pv = __builtin_amdgcn_exp2f(acc[i][j][r] - mb);
        u16 h = f2bf(pv);
        ls += bf2f(h);
        P[R * N_TOK + (cb * 128 + wn * 64 + j * 16 + l15)] = h;
      }
#pragma unroll
      for (int off = 1; off <= 8; off <<= 1) ls += __shfl_xor(ls, off, 64);
      lsum[i][r] = ls;
    }
  // write per-wave sums
#pragma unroll
  for (int i = 0; i < 4; ++i)
#pragma unroll
    for (int r = 0; r < 4; ++r)
      if (l15 == 0) Lw[wn][wm * 64 + i * 16 + l4 * 4 + r] = lsum[i][r];
  __syncthreads();
  if (t < 128) {
    Mpart[(size_t)cb * N_TOK + rb * 128 + t] = fmaxf(Mw[0][t], Mw[1][t]);
    Lpart[(size_t)cb * N_TOK + rb * 128 + t] = Lw[0][t] + Lw[1][t];
  }
}

// ---------------- row stats: m, 1/l ----------------
__global__ __launch_bounds__(256, 4) void rowstats(const float* __restrict__ Mpart,
                                                   const float* __restrict__ Lpart,
                                                   float* __restrict__ m_row,
                                                   float* __restrict__ linv) {
  const int r = blockIdx.x * 256 + threadIdx.x;
  float m = -INFINITY;
#pragma unroll 8
  for (int tb = 0; tb < 64; ++tb) m = fmaxf(m, Mpart[(size_t)tb * N_TOK + r]);
  float l = 0.f;
#pragma unroll 8
  for (int tb = 0; tb < 64; ++tb)
    l += __builtin_amdgcn_exp2f(Mpart[(size_t)tb * N_TOK + r] - m) *
         Lpart[(size_t)tb * N_TOK + r];
  m_row[r] = m;
  linv[r] = 1.0f / l;
}

// ---------------- scale P' by exp2(mb - m), in place ----------------
__global__ __launch_bounds__(256, 4) void scale_p(u16* __restrict__ P,
                                                  const float* __restrict__ Mpart,
                                                  const float* __restrict__ m_row) {
  const int r = blockIdx.x;
  const int j = threadIdx.x;          // 32 cols per thread
  const float m = m_row[r];
  const float f = __builtin_amdgcn_exp2f(Mpart[(size_t)(j >> 2) * N_TOK + r] - m);
  u16* p = P + (size_t)r * N_TOK + j * 32;
#pragma unroll
  for (int c = 0; c < 4; ++c) {
    uint4 v = *(uint4*)(p + c * 8);
    unsigned vv[4] = {v.x, v.y, v.z, v.w};
#pragma unroll
    for (int q = 0; q < 4; ++q) {
      u16 lo = (u16)(vv[q] & 0xffffu), hi = (u16)(vv[q] >> 16);
      lo = f2bf(bf2f(lo) * f);
      hi = f2bf(bf2f(hi) * f);
      vv[q] = (unsigned)lo | ((unsigned)hi << 16);
    }
    v.x = vv[0]; v.y = vv[1]; v.z = vv[2]; v.w = vv[3];
    *(uint4*)(p + c * 8) = v;
  }
}

// ---------------- Pass O: Out = (P' @ Xt^T) * linv ----------------
__global__ __launch_bounds__(256, 2) void gemm_o(const u16* __restrict__ P,
                                                 const u16* __restrict__ Xt,
                                                 const float* __restrict__ linv,
                                                 float* __restrict__ Out) {
  __shared__ u16 T[2][128 * 32];  // A (P rows), B (Xt rows = out cols)
  const int t = threadIdx.x, w = t >> 6, l = t & 63;
  const int l15 = l & 15, l4 = l >> 4;
  const int nb = blockIdx.x, rb = blockIdx.y;
  const int wm = w & 1, wn = w >> 1;

  const u16* sbase = (w < 2) ? P + ((size_t)rb * 128 + (w & 1) * 64) * N_TOK
                             : Xt + ((size_t)nb * 128 + (w & 1) * 64) * N_TOK;
  const u16* mysrc = sbase + (size_t)(l >> 2) * N_TOK + (l & 3) * 8;
  u16* myT = &T[w >> 1][(w & 1) * 2048];

  floatx4 acc[4][4] = {};

  for (int k0 = 0; k0 < N_TOK; k0 += 32) {
    __syncthreads();
#pragma unroll
    for (int n = 0; n < 4; ++n)
      gload_lds16(mysrc + (size_t)n * 16 * N_TOK + k0, myT + n * 512);
    __syncthreads();
    bf16x8 af[4], bf[4];
#pragma unroll
    for (int i = 0; i < 4; ++i) {
      af[i] = *(const bf16x8*)&T[0][(wm * 64 + i * 16 + l15) * 32 + l4 * 8];
      bf[i] = *(const bf16x8*)&T[1][(wn * 64 + i * 16 + l15) * 32 + l4 * 8];
    }
#pragma unroll
    for (int i = 0; i < 4; ++i)
#pragma unroll
      for (int j = 0; j < 4; ++j) acc[i][j] = mfma16(af[i], bf[j], acc[i][j]);
  }

#pragma unroll
  for (int i = 0; i < 4; ++i)
#pragma unroll
    for (int r = 0; r < 4; ++r) {
      int R = rb * 128 + wm * 64 + i * 16 + l4 * 4 + r;
      float inv = linv[R];
      float* orow = Out + (size_t)R * DIM + nb * 128 + wn * 64 + l15;
#pragma unroll
      for (int j = 0; j < 4; ++j) orow[j * 16] = acc[i][j][r] * inv;
    }
}

extern "C" void kernel_launch(void* const* d_in, const int* in_sizes, int n_in,
                              void* d_out, int out_size, void* d_ws, size_t ws_size,
                              hipStream_t stream) {
  const float* Wq = (const float*)d_in[0];
  const float* Wk = (const float*)d_in[1];
  const float* X  = (const float*)d_in[2];
  float* Out = (float*)d_out;

  constexpr size_t MAT = (size_t)N_TOK * DIM;  // 8 Mi elems
  u16* Qhi = (u16*)d_ws;
  u16* Qlo = Qhi + MAT;
  u16* Khi = Qlo + MAT;
  u16* Klo = Khi + MAT;
  u16* Xt  = Klo + MAT;
  u16* P   = Xt + MAT;                          // 8192x8192 bf16 = 128 MB
  float* Mpart = (float*)(P + (size_t)N_TOK * N_TOK);  // 64 x 8192
  float* Lpart = Mpart + (size_t)64 * N_TOK;
  float* m_row = Lpart + (size_t)64 * N_TOK;
  float* linv  = m_row + N_TOK;                 // total ~212 MB

  dim3 gproj(DIM / 128, N_TOK / 128);
  sgemm_split<<<gproj, 256, 0, stream>>>(X, Wq, Qhi, Qlo);
  sgemm_split<<<gproj, 256, 0, stream>>>(X, Wk, Khi, Klo);
  transpose_bf16<<<dim3(N_TOK / 64, DIM / 64), 256, 0, stream>>>(X, Xt);
  gemm_s<<<dim3(64, 64), 256, 0, stream>>>(Qhi, Qlo, Khi, Klo, P, Mpart, Lpart);
  rowstats<<<dim3(32), 256, 0, stream>>>(Mpart, Lpart, m_row, linv);
  scale_p<<<dim3(N_TOK), 256, 0, stream>>>(P, Mpart, m_row);
  gemm_o<<<dim3(DIM / 128, N_TOK / 128), 256, 0, stream>>>(P, Xt, linv, Out);
}

// Round 4
// 900.765 us; speedup vs baseline: 18.0464x; 1.3162x over previous
//
#include <hip/hip_runtime.h>
#include <math.h>

typedef unsigned short u16;
typedef __bf16 bf16x8 __attribute__((ext_vector_type(8)));
typedef float floatx4 __attribute__((ext_vector_type(4)));

constexpr int N_TOK = 8192;
constexpr int DIM   = 1024;
// softmax in exp2 domain: s2 = dot * (1/sqrt(1024)) * log2(e)
constexpr float SC2 = 0.03125f * 1.4426950408889634f;

__device__ __forceinline__ u16 f2bf(float f) {
  unsigned u = __builtin_bit_cast(unsigned, f);
  unsigned r = u + 0x7fffu + ((u >> 16) & 1u);  // round-to-nearest-even
  return (u16)(r >> 16);
}
__device__ __forceinline__ float bf2f(u16 h) {
  unsigned u = ((unsigned)h) << 16;
  return __builtin_bit_cast(float, u);
}
__device__ __forceinline__ floatx4 mfma16(bf16x8 a, bf16x8 b, floatx4 c) {
  return __builtin_amdgcn_mfma_f32_16x16x32_bf16(a, b, c, 0, 0, 0);
}
// async global->LDS, 16B per lane; LDS side is wave-uniform base + lane*16.
__device__ __forceinline__ void gload_lds16(const void* g, void* l) {
  using GP = const unsigned __attribute__((address_space(1)))*;
  using LP = unsigned __attribute__((address_space(3)))*;
  __builtin_amdgcn_global_load_lds((GP)(uintptr_t)g, (LP)(uintptr_t)l, 16, 0, 0);
}

// ---------------- X -> Xhi/Xlo (row-major) + Xt (bf16 hi, [DIM][N_TOK]) ----
__global__ __launch_bounds__(256, 4) void split_x(const float* __restrict__ X,
                                                  u16* __restrict__ Xhi,
                                                  u16* __restrict__ Xlo,
                                                  u16* __restrict__ Xt) {
  __shared__ u16 T[64][72];
  const int tok0 = blockIdx.x * 64, d0 = blockIdx.y * 64;
  const int t = threadIdx.x;
  {
    const int tok = t >> 2, dc = (t & 3) * 16;
    const float* src = X + (size_t)(tok0 + tok) * DIM + d0 + dc;
    u16 h[16], lo[16];
#pragma unroll
    for (int c = 0; c < 16; c += 4) {
      float4 v = *(const float4*)(src + c);
      float vv[4] = {v.x, v.y, v.z, v.w};
#pragma unroll
      for (int q = 0; q < 4; ++q) {
        h[c + q] = f2bf(vv[q]);
        lo[c + q] = f2bf(vv[q] - bf2f(h[c + q]));
        T[dc + c + q][tok] = h[c + q];
      }
    }
    uint4 hv, lv;
    unsigned* hp = (unsigned*)&hv; unsigned* lp = (unsigned*)&lv;
#pragma unroll
    for (int q = 0; q < 4; ++q) {
      hp[q] = (unsigned)h[q * 2] | ((unsigned)h[q * 2 + 1] << 16);
      lp[q] = (unsigned)lo[q * 2] | ((unsigned)lo[q * 2 + 1] << 16);
    }
    size_t off = (size_t)(tok0 + tok) * DIM + d0 + dc;
    *(uint4*)(Xhi + off) = hv;
    *(uint4*)(Xlo + off) = lv;
#pragma unroll
    for (int q = 0; q < 4; ++q) {
      hp[q] = (unsigned)h[8 + q * 2] | ((unsigned)h[8 + q * 2 + 1] << 16);
      lp[q] = (unsigned)lo[8 + q * 2] | ((unsigned)lo[8 + q * 2 + 1] << 16);
    }
    *(uint4*)(Xhi + off + 8) = hv;
    *(uint4*)(Xlo + off + 8) = lv;
  }
  __syncthreads();
  {
    const int d = t >> 3, tk = (t & 7) * 8;
#pragma unroll
    for (int rep = 0; rep < 2; ++rep) {
      int dd = d + rep * 32;
      *(uint4*)(Xt + (size_t)(d0 + dd) * N_TOK + tok0 + tk) = *(uint4*)&T[dd][tk];
    }
  }
}

// ---------------- W[k][n] -> Wt_hi/Wt_lo [n][k] (bf16 split) --------------
__global__ __launch_bounds__(256, 4) void split_wt(const float* __restrict__ W0,
                                                   const float* __restrict__ W1,
                                                   u16* __restrict__ Whi,
                                                   u16* __restrict__ Wlo) {
  __shared__ float Tf[64][65];
  const int k0 = blockIdx.x * 64, n0 = blockIdx.y * 64;
  const int sel = blockIdx.z;
  const float* W = sel ? W1 : W0;
  u16* Oh = Whi + (size_t)sel * DIM * DIM;
  u16* Ol = Wlo + (size_t)sel * DIM * DIM;
  const int t = threadIdx.x;
  {
    const int k = t >> 2, nc = (t & 3) * 16;
    const float* src = W + (size_t)(k0 + k) * DIM + n0 + nc;
#pragma unroll
    for (int c = 0; c < 16; c += 4) {
      float4 v = *(const float4*)(src + c);
      Tf[nc + c + 0][k] = v.x;
      Tf[nc + c + 1][k] = v.y;
      Tf[nc + c + 2][k] = v.z;
      Tf[nc + c + 3][k] = v.w;
    }
  }
  __syncthreads();
  {
    const int n = t >> 3, kk = (t & 7) * 8;
#pragma unroll
    for (int rep = 0; rep < 2; ++rep) {
      int nn = n + rep * 32;
      uint4 hv, lv;
      unsigned* hp = (unsigned*)&hv; unsigned* lp = (unsigned*)&lv;
#pragma unroll
      for (int q = 0; q < 4; ++q) {
        u16 h0, l0, h1, l1;
        float a = Tf[nn][kk + q * 2], b = Tf[nn][kk + q * 2 + 1];
        h0 = f2bf(a); l0 = f2bf(a - bf2f(h0));
        h1 = f2bf(b); l1 = f2bf(b - bf2f(h1));
        hp[q] = (unsigned)h0 | ((unsigned)h1 << 16);
        lp[q] = (unsigned)l0 | ((unsigned)l1 << 16);
      }
      size_t off = (size_t)(n0 + nn) * DIM + k0 + kk;
      *(uint4*)(Oh + off) = hv;
      *(uint4*)(Ol + off) = lv;
    }
  }
}

// ---------------- Fused projections: {Q,K} = X @ {Wq,Wk}, split-3 MFMA ----
// grid (16, 64): nb<8 -> Q cols nb*128; nb>=8 -> K cols (nb-8)*128.
__global__ __launch_bounds__(256, 2) void gemm_proj(const u16* __restrict__ Xhi,
                                                    const u16* __restrict__ Xlo,
                                                    const u16* __restrict__ Wthi,
                                                    const u16* __restrict__ Wtlo,
                                                    u16* __restrict__ Qhi,
                                                    u16* __restrict__ Qlo,
                                                    u16* __restrict__ Khi,
                                                    u16* __restrict__ Klo) {
  __shared__ u16 T[4][128 * 32];
  const int t = threadIdx.x, w = t >> 6, l = t & 63;
  const int l15 = l & 15, l4 = l >> 4;
  const int nb = blockIdx.x, rb = blockIdx.y;
  const int sel = nb >> 3, col0 = (nb & 7) * 128;
  const int wm = w & 1, wn = w >> 1;
  const int sl = l4 ^ (l15 & 3);  // swizzled k-slot for fragment reads

  const u16* sbase;
  if (w == 0)      sbase = Xhi + (size_t)rb * 128 * DIM;
  else if (w == 1) sbase = Xlo + (size_t)rb * 128 * DIM;
  else if (w == 2) sbase = Wthi + (size_t)sel * DIM * DIM + (size_t)col0 * DIM;
  else             sbase = Wtlo + (size_t)sel * DIM * DIM + (size_t)col0 * DIM;
  // stage k-group (l&3)^((l>>2)&3) so LDS slot (l&3) holds swizzled data
  const u16* mysrc = sbase + (size_t)(l >> 2) * DIM + (((l & 3) ^ ((l >> 2) & 3)) * 8);

  floatx4 acc[4][4] = {};

  for (int k0 = 0; k0 < DIM; k0 += 32) {
    __syncthreads();
#pragma unroll
    for (int n = 0; n < 8; ++n)
      gload_lds16(mysrc + (size_t)n * 16 * DIM + k0, &T[w][n * 512]);
    __syncthreads();
    bf16x8 aH[4], aL[4], bH[4], bL[4];
#pragma unroll
    for (int i = 0; i < 4; ++i) {
      int ar = wm * 64 + i * 16 + l15;
      aH[i] = *(const bf16x8*)&T[0][ar * 32 + sl * 8];
      aL[i] = *(const bf16x8*)&T[1][ar * 32 + sl * 8];
      int br = wn * 64 + i * 16 + l15;
      bH[i] = *(const bf16x8*)&T[2][br * 32 + sl * 8];
      bL[i] = *(const bf16x8*)&T[3][br * 32 + sl * 8];
    }
#pragma unroll
    for (int i = 0; i < 4; ++i)
#pragma unroll
      for (int j = 0; j < 4; ++j) {
        acc[i][j] = mfma16(aL[i], bH[j], acc[i][j]);
        acc[i][j] = mfma16(aH[i], bL[j], acc[i][j]);
        acc[i][j] = mfma16(aH[i], bH[j], acc[i][j]);
      }
  }

  u16* Oh = sel ? Khi : Qhi;
  u16* Ol = sel ? Klo : Qlo;
#pragma unroll
  for (int i = 0; i < 4; ++i)
#pragma unroll
    for (int r = 0; r < 4; ++r) {
      size_t R = (size_t)(rb * 128 + wm * 64 + i * 16 + l4 * 4 + r);
#pragma unroll
      for (int j = 0; j < 4; ++j) {
        float v = acc[i][j][r];
        u16 h = f2bf(v);
        u16 lo = f2bf(v - bf2f(h));
        size_t off = R * DIM + (col0 + wn * 64 + j * 16 + l15);
        Oh[off] = h;
        Ol[off] = lo;
      }
    }
}

// ---------------- Pass S: P' = exp2(QK^T*SC2 - mb), Mpart, Lpart ---------
__global__ __launch_bounds__(256, 2) void gemm_s(const u16* __restrict__ Qhi,
                                                 const u16* __restrict__ Qlo,
                                                 const u16* __restrict__ Khi,
                                                 const u16* __restrict__ Klo,
                                                 u16* __restrict__ P,
                                                 float* __restrict__ Mpart,
                                                 float* __restrict__ Lpart) {
  __shared__ u16 T[4][128 * 32];  // Ahi, Alo, Bhi, Blo
  __shared__ float Mw[2][128], Lw[2][128];
  const int t = threadIdx.x, w = t >> 6, l = t & 63;
  const int l15 = l & 15, l4 = l >> 4;
  const int cb = blockIdx.x, rb = blockIdx.y;
  const int wm = w & 1, wn = w >> 1;
  const int sl = l4 ^ (l15 & 3);

  const u16* sbase;
  if (w == 0)      sbase = Qhi + (size_t)rb * 128 * DIM;
  else if (w == 1) sbase = Qlo + (size_t)rb * 128 * DIM;
  else if (w == 2) sbase = Khi + (size_t)cb * 128 * DIM;
  else             sbase = Klo + (size_t)cb * 128 * DIM;
  const u16* mysrc = sbase + (size_t)(l >> 2) * DIM + (((l & 3) ^ ((l >> 2) & 3)) * 8);

  floatx4 acc[4][4] = {};

  for (int k0 = 0; k0 < DIM; k0 += 32) {
    __syncthreads();
#pragma unroll
    for (int n = 0; n < 8; ++n)
      gload_lds16(mysrc + (size_t)n * 16 * DIM + k0, &T[w][n * 512]);
    __syncthreads();
    bf16x8 aH[4], aL[4], bH[4], bL[4];
#pragma unroll
    for (int i = 0; i < 4; ++i) {
      int ar = wm * 64 + i * 16 + l15;
      aH[i] = *(const bf16x8*)&T[0][ar * 32 + sl * 8];
      aL[i] = *(const bf16x8*)&T[1][ar * 32 + sl * 8];
      int br = wn * 64 + i * 16 + l15;
      bH[i] = *(const bf16x8*)&T[2][br * 32 + sl * 8];
      bL[i] = *(const bf16x8*)&T[3][br * 32 + sl * 8];
    }
#pragma unroll
    for (int i = 0; i < 4; ++i)
#pragma unroll
      for (int j = 0; j < 4; ++j) {
        acc[i][j] = mfma16(aL[i], bH[j], acc[i][j]);
        acc[i][j] = mfma16(aH[i], bL[j], acc[i][j]);
        acc[i][j] = mfma16(aH[i], bH[j], acc[i][j]);
      }
  }

  // ---- epilogue ----
#pragma unroll
  for (int i = 0; i < 4; ++i)
#pragma unroll
    for (int j = 0; j < 4; ++j)
#pragma unroll
      for (int r = 0; r < 4; ++r) acc[i][j][r] *= SC2;

  float mrow[4][4];
#pragma unroll
  for (int i = 0; i < 4; ++i)
#pragma unroll
    for (int r = 0; r < 4; ++r) {
      float m = fmaxf(fmaxf(acc[i][0][r], acc[i][1][r]),
                      fmaxf(acc[i][2][r], acc[i][3][r]));
#pragma unroll
      for (int off = 1; off <= 8; off <<= 1) m = fmaxf(m, __shfl_xor(m, off, 64));
      mrow[i][r] = m;
      if (l15 == 0) Mw[wn][wm * 64 + i * 16 + l4 * 4 + r] = m;
    }
  __syncthreads();
  float lsum[4][4];
#pragma unroll
  for (int i = 0; i < 4; ++i)
#pragma unroll
    for (int r = 0; r < 4; ++r) {
      int lr = wm * 64 + i * 16 + l4 * 4 + r;
      float mb = fmaxf(Mw[0][lr], Mw[1][lr]);
      float ls = 0.f;
      size_t R = (size_t)(rb * 128 + lr);
#pragma unroll
      for (int j = 0; j < 4; ++j) {
        float pv = __builtin_amdgcn_exp2f(acc[i][j][r] - mb);
        u16 h = f2bf(pv);
        ls += bf2f(h);
        P[R * N_TOK + (cb * 128 + wn * 64 + j * 16 + l15)] = h;
      }
#pragma unroll
      for (int off = 1; off <= 8; off <<= 1) ls += __shfl_xor(ls, off, 64);
      lsum[i][r] = ls;
    }
#pragma unroll
  for (int i = 0; i < 4; ++i)
#pragma unroll
    for (int r = 0; r < 4; ++r)
      if (l15 == 0) Lw[wn][wm * 64 + i * 16 + l4 * 4 + r] = lsum[i][r];
  __syncthreads();
  if (t < 128) {
    Mpart[(size_t)cb * N_TOK + rb * 128 + t] = fmaxf(Mw[0][t], Mw[1][t]);
    Lpart[(size_t)cb * N_TOK + rb * 128 + t] = Lw[0][t] + Lw[1][t];
  }
}

// ---------------- row stats: m, 1/l ----------------
__global__ __launch_bounds__(256, 4) void rowstats(const float* __restrict__ Mpart,
                                                   const float* __restrict__ Lpart,
                                                   float* __restrict__ m_row,
                                                   float* __restrict__ linv) {
  const int r = blockIdx.x * 256 + threadIdx.x;
  float m = -INFINITY;
#pragma unroll 8
  for (int tb = 0; tb < 64; ++tb) m = fmaxf(m, Mpart[(size_t)tb * N_TOK + r]);
  float l = 0.f;
#pragma unroll 8
  for (int tb = 0; tb < 64; ++tb)
    l += __builtin_amdgcn_exp2f(Mpart[(size_t)tb * N_TOK + r] - m) *
         Lpart[(size_t)tb * N_TOK + r];
  m_row[r] = m;
  linv[r] = 1.0f / l;
}

// ---------------- scale P' by exp2(mb - m), in place ----------------
__global__ __launch_bounds__(256, 4) void scale_p(u16* __restrict__ P,
                                                  const float* __restrict__ Mpart,
                                                  const float* __restrict__ m_row) {
  const int r = blockIdx.x;
  const int j = threadIdx.x;
  const float m = m_row[r];
  const float f = __builtin_amdgcn_exp2f(Mpart[(size_t)(j >> 2) * N_TOK + r] - m);
  u16* p = P + (size_t)r * N_TOK + j * 32;
#pragma unroll
  for (int c = 0; c < 4; ++c) {
    uint4 v = *(uint4*)(p + c * 8);
    unsigned vv[4] = {v.x, v.y, v.z, v.w};
#pragma unroll
    for (int q = 0; q < 4; ++q) {
      u16 lo = (u16)(vv[q] & 0xffffu), hi = (u16)(vv[q] >> 16);
      lo = f2bf(bf2f(lo) * f);
      hi = f2bf(bf2f(hi) * f);
      vv[q] = (unsigned)lo | ((unsigned)hi << 16);
    }
    v.x = vv[0]; v.y = vv[1]; v.z = vv[2]; v.w = vv[3];
    *(uint4*)(p + c * 8) = v;
  }
}

// ---------------- Pass O: Out = (P' @ Xt^T) * linv ----------------
__global__ __launch_bounds__(256, 2) void gemm_o(const u16* __restrict__ P,
                                                 const u16* __restrict__ Xt,
                                                 const float* __restrict__ linv,
                                                 float* __restrict__ Out) {
  __shared__ u16 T[2][128 * 32];
  const int t = threadIdx.x, w = t >> 6, l = t & 63;
  const int l15 = l & 15, l4 = l >> 4;
  const int nb = blockIdx.x, rb = blockIdx.y;
  const int wm = w & 1, wn = w >> 1;
  const int sl = l4 ^ (l15 & 3);

  const u16* sbase = (w < 2) ? P + ((size_t)rb * 128 + (w & 1) * 64) * N_TOK
                             : Xt + ((size_t)nb * 128 + (w & 1) * 64) * N_TOK;
  const u16* mysrc = sbase + (size_t)(l >> 2) * N_TOK + (((l & 3) ^ ((l >> 2) & 3)) * 8);
  u16* myT = &T[w >> 1][(w & 1) * 2048];

  floatx4 acc[4][4] = {};

  for (int k0 = 0; k0 < N_TOK; k0 += 32) {
    __syncthreads();
#pragma unroll
    for (int n = 0; n < 4; ++n)
      gload_lds16(mysrc + (size_t)n * 16 * N_TOK + k0, myT + n * 512);
    __syncthreads();
    bf16x8 af[4], bf[4];
#pragma unroll
    for (int i = 0; i < 4; ++i) {
      af[i] = *(const bf16x8*)&T[0][(wm * 64 + i * 16 + l15) * 32 + sl * 8];
      bf[i] = *(const bf16x8*)&T[1][(wn * 64 + i * 16 + l15) * 32 + sl * 8];
    }
#pragma unroll
    for (int i = 0; i < 4; ++i)
#pragma unroll
      for (int j = 0; j < 4; ++j) acc[i][j] = mfma16(af[i], bf[j], acc[i][j]);
  }

#pragma unroll
  for (int i = 0; i < 4; ++i)
#pragma unroll
    for (int r = 0; r < 4; ++r) {
      int R = rb * 128 + wm * 64 + i * 16 + l4 * 4 + r;
      float inv = linv[R];
      float* orow = Out + (size_t)R * DIM + nb * 128 + wn * 64 + l15;
#pragma unroll
      for (int j = 0; j < 4; ++j) orow[j * 16] = acc[i][j][r] * inv;
    }
}

extern "C" void kernel_launch(void* const* d_in, const int* in_sizes, int n_in,
                              void* d_out, int out_size, void* d_ws, size_t ws_size,
                              hipStream_t stream) {
  const float* Wq = (const float*)d_in[0];
  const float* Wk = (const float*)d_in[1];
  const float* X  = (const float*)d_in[2];
  float* Out = (float*)d_out;

  constexpr size_t MAT = (size_t)N_TOK * DIM;   // 8 Mi elems
  constexpr size_t WMAT = (size_t)DIM * DIM;    // 1 Mi elems
  u16* Qhi = (u16*)d_ws;
  u16* Qlo = Qhi + MAT;
  u16* Khi = Qlo + MAT;
  u16* Klo = Khi + MAT;
  u16* Xt  = Klo + MAT;
  u16* Xhi = Xt + MAT;
  u16* Xlo = Xhi + MAT;
  u16* Wthi = Xlo + MAT;          // [2][1024][1024]
  u16* Wtlo = Wthi + 2 * WMAT;
  u16* P   = Wtlo + 2 * WMAT;     // 8192x8192 bf16 = 128 MB
  float* Mpart = (float*)(P + (size_t)N_TOK * N_TOK);
  float* Lpart = Mpart + (size_t)64 * N_TOK;
  float* m_row = Lpart + (size_t)64 * N_TOK;
  float* linv  = m_row + N_TOK;

  split_x<<<dim3(N_TOK / 64, DIM / 64), 256, 0, stream>>>(X, Xhi, Xlo, Xt);
  split_wt<<<dim3(DIM / 64, DIM / 64, 2), 256, 0, stream>>>(Wq, Wk, Wthi, Wtlo);
  gemm_proj<<<dim3(16, 64), 256, 0, stream>>>(Xhi, Xlo, Wthi, Wtlo,
                                              Qhi, Qlo, Khi, Klo);
  gemm_s<<<dim3(64, 64), 256, 0, stream>>>(Qhi, Qlo, Khi, Klo, P, Mpart, Lpart);
  rowstats<<<dim3(32), 256, 0, stream>>>(Mpart, Lpart, m_row, linv);
  scale_p<<<dim3(N_TOK), 256, 0, stream>>>(P, Mpart, m_row);
  gemm_o<<<dim3(DIM / 128, N_TOK / 128), 256, 0, stream>>>(P, Xt, linv, Out);
}